// Round 1
// baseline (1419.340 us; speedup 1.0000x reference)
//
#include <hip/hip_runtime.h>
#include <hip/hip_bf16.h>

typedef __bf16 bf16;
typedef __bf16 bf16x8 __attribute__((ext_vector_type(8)));
typedef float f32x4 __attribute__((ext_vector_type(4)));

#define MFMA16(a, b, c) __builtin_amdgcn_mfma_f32_16x16x32_bf16(a, b, c, 0, 0, 0)

// B=16, H=W=128, C=192, WS=8, SHIFT=4, HEADS=6, N=64 -> nW=256/img, 4096 windows
#define SCALE_Q 0.17677669529663687f

// ---------------- K0: weight fp32->bf16 + rpb bias table expansion ----------------
__global__ __launch_bounds__(256) void prep_kernel(
    const float* __restrict__ qkv_w, const float* __restrict__ proj_w,
    const float* __restrict__ fc1_w, const float* __restrict__ fc2_w,
    const float* __restrict__ rpb,
    bf16* __restrict__ wqkv, bf16* __restrict__ wproj,
    bf16* __restrict__ wfc1, bf16* __restrict__ wfc2,
    float* __restrict__ bias_full) {
  const int i = blockIdx.x * 256 + threadIdx.x;
  if (i < 110592) wqkv[i] = (bf16)qkv_w[i];
  if (i < 36864)  wproj[i] = (bf16)proj_w[i];
  if (i < 147456) { wfc1[i] = (bf16)fc1_w[i]; wfc2[i] = (bf16)fc2_w[i]; }
  if (i < 24576) {
    const int head = i >> 12;           // [6][64][64]
    const int row = (i >> 6) & 63, col = i & 63;
    const int idx = ((row >> 3) - (col >> 3) + 7) * 15 + ((row & 7) - (col & 7) + 7);
    bias_full[i] = rpb[idx * 6 + head];
  }
}

__device__ __forceinline__ int region8(int tok, int wy, int wx) {
  const int gh = wy * 8 + (tok >> 3), gw = wx * 8 + (tok & 7);
  const int rs = (gh < 120) ? 0 : ((gh < 124) ? 1 : 2);
  const int cs = (gw < 120) ? 0 : ((gw < 124) ? 1 : 2);
  return rs * 3 + cs;
}

// ---------------- K1: whole Swin block, 1 window per 384-thread block ----------------
// LDS region map (bytes), phase-aliased; high water 80896 -> 2 blocks/CU:
//   [0,25600)      a_s   bf16 [64][200]        ph1-2a
//   [0,24576)      q_s   bf16 [6][64][32]      ph2b-3a (over a_s, after barrier)
//   [24576,49152)  k_s   bf16 [6][64][32]      ph2b-3a
//   [49152,73728)  vT_s  bf16 [6][32][64]      ph2b-3
//   [0,49152)      p_s   bf16 [6][64][64] XOR  ph3b (over q+k, after barrier)
//   [0,25600)      ao_s  bf16 [64][200]        ph4 (over p heads 0-2, after barrier)
//   [25600,29696)  red_s f32  [64][16]         ph5 (LN2 partials)
//   [29696,55296)  m_s   bf16 [64][200]        ph5-6
//   [55296,80896)  g_s   bf16 [64][200]        ph6
// residual h lives in registers: hreg[4][2][4] per thread (rows 16i+4q+r, cols wid*32+16j+c)
__global__ __launch_bounds__(384, 3) void swin_block_kernel(
    const float* __restrict__ x,
    const float* __restrict__ n1g, const float* __restrict__ n1b,
    const bf16* __restrict__ wqkv, const float* __restrict__ qkv_b,
    const bf16* __restrict__ wproj, const float* __restrict__ proj_b,
    const float* __restrict__ bias_full,
    const float* __restrict__ n2g, const float* __restrict__ n2b,
    const bf16* __restrict__ wfc1, const float* __restrict__ fc1_b,
    const bf16* __restrict__ wfc2, const float* __restrict__ fc2_b,
    float* __restrict__ out) {
  __shared__ __align__(16) char smem[80896];
  bf16*  a_s  = (bf16*)(smem);
  bf16*  q_s  = (bf16*)(smem);
  bf16*  k_s  = (bf16*)(smem + 24576);
  bf16*  vT_s = (bf16*)(smem + 49152);
  bf16*  ao_s = (bf16*)(smem);
  float* red_s = (float*)(smem + 25600);
  bf16*  m_s  = (bf16*)(smem + 29696);
  bf16*  g_s  = (bf16*)(smem + 55296);

  const int lane = threadIdx.x & 63, waveid = threadIdx.x >> 6;
  const int c = lane & 15, quad = lane >> 4;
  const int window = blockIdx.x;
  const int bi = window >> 8, w_in = window & 255;
  const int wy = w_in >> 4, wx = w_in & 15;
  const f32x4 fzero = {0.f, 0.f, 0.f, 0.f};

  // swizzled P accessor: [head][row][col] bf16, pitch 64, byte ^= (row&7)<<4
  auto p_ptr = [&](int head, int row, int colbyte) -> bf16* {
    int off = (row << 7) + colbyte;
    off ^= (row & 7) << 4;
    return (bf16*)(smem + (head << 13) + off);
  };

  // ---- ph1: LN1 + roll(-4,-4) gather -> a_s ----
  for (int it = 0; it < 11; it++) {
    const int n = waveid * 11 + it;
    if (n < 64) {
      const int oh = (wy * 8 + (n >> 3) + 4) & 127;
      const int ow = (wx * 8 + (n & 7) + 4) & 127;
      const float* xr = x + (size_t)(bi * 16384 + oh * 128 + ow) * 192;
      float v0 = xr[lane], v1 = xr[lane + 64], v2 = xr[lane + 128];
      float s = v0 + v1 + v2;
      float s2 = v0 * v0 + v1 * v1 + v2 * v2;
#pragma unroll
      for (int off = 1; off < 64; off <<= 1) {
        s += __shfl_xor(s, off);
        s2 += __shfl_xor(s2, off);
      }
      const float mu = s * (1.f / 192.f);
      const float rinv = rsqrtf(s2 * (1.f / 192.f) - mu * mu + 1e-5f);
      a_s[n * 200 + lane]       = (bf16)((v0 - mu) * rinv * n1g[lane]       + n1b[lane]);
      a_s[n * 200 + lane + 64]  = (bf16)((v1 - mu) * rinv * n1g[lane + 64]  + n1b[lane + 64]);
      a_s[n * 200 + lane + 128] = (bf16)((v2 - mu) * rinv * n1g[lane + 128] + n1b[lane + 128]);
    }
  }
  __syncthreads();

  // ---- ph2: qkv GEMM (wave covers 96 cols = one tensor x one head pair) ----
  // Accumulate fully in regs; barrier; then scatter q/k/vT OVER the a_s region.
  {
    f32x4 acc[4][6];
#pragma unroll
    for (int i = 0; i < 4; i++)
#pragma unroll
      for (int j = 0; j < 6; j++) acc[i][j] = fzero;
#pragma unroll
    for (int ks = 0; ks < 6; ks++) {
      bf16x8 a[4], w[6];
#pragma unroll
      for (int i = 0; i < 4; i++)
        a[i] = *(const bf16x8*)&a_s[(16 * i + c) * 200 + ks * 32 + quad * 8];
#pragma unroll
      for (int j = 0; j < 6; j++)
        w[j] = *(const bf16x8*)(wqkv +
            (size_t)(waveid * 96 + 16 * j + c) * 192 + ks * 32 + quad * 8);
#pragma unroll
      for (int i = 0; i < 4; i++)
#pragma unroll
        for (int j = 0; j < 6; j++) acc[i][j] = MFMA16(a[i], w[j], acc[i][j]);
    }
    __syncthreads();   // A: all a_s reads complete before q/k overwrite it
    const int which = waveid >> 1;   // 0=q 1=k 2=v (wave-uniform)
#pragma unroll
    for (int j = 0; j < 6; j++) {
      const int col = waveid * 96 + 16 * j + c;
      const int sub = col - which * 192;
      const int head = sub >> 5, d = sub & 31;
      const float bias = qkv_b[col];
#pragma unroll
      for (int i = 0; i < 4; i++)
#pragma unroll
        for (int r = 0; r < 4; r++) {
          const int n = 16 * i + 4 * quad + r;
          const float val = acc[i][j][r] + bias;
          if (which == 0)      q_s[head * 2048 + n * 32 + d] = (bf16)(val * SCALE_Q);
          else if (which == 1) k_s[head * 2048 + n * 32 + d] = (bf16)val;
          else                 vT_s[head * 2048 + d * 64 + n] = (bf16)val;
        }
    }
  }
  __syncthreads();   // B: q/k/vT visible to all waves

  // ---- ph3: attention, wave = head ----
  f32x4 o[4][2];
  {
    const int head = waveid;
    bf16x8 aq[4], bk[4];
#pragma unroll
    for (int i = 0; i < 4; i++)
      aq[i] = *(const bf16x8*)&q_s[head * 2048 + (16 * i + c) * 32 + quad * 8];
#pragma unroll
    for (int j = 0; j < 4; j++)
      bk[j] = *(const bf16x8*)&k_s[head * 2048 + (16 * j + c) * 32 + quad * 8];
    __syncthreads();   // C: all q/k fragment loads landed; P may overwrite q/k

    f32x4 s[4][4];
#pragma unroll
    for (int i = 0; i < 4; i++)
#pragma unroll
      for (int j = 0; j < 4; j++) s[i][j] = fzero;
#pragma unroll
    for (int i = 0; i < 4; i++)
#pragma unroll
      for (int j = 0; j < 4; j++) s[i][j] = MFMA16(aq[i], bk[j], s[i][j]);

    const float* bfp = bias_full + head * 4096;
#pragma unroll
    for (int i = 0; i < 4; i++)
#pragma unroll
      for (int r = 0; r < 4; r++) {
        const int row = 16 * i + 4 * quad + r;
#pragma unroll
        for (int j = 0; j < 4; j++) s[i][j][r] += bfp[row * 64 + 16 * j + c];
      }

    if (wy == 15 || wx == 15) {
      int creg[4];
#pragma unroll
      for (int j = 0; j < 4; j++) creg[j] = region8(16 * j + c, wy, wx);
#pragma unroll
      for (int i = 0; i < 4; i++)
#pragma unroll
        for (int r = 0; r < 4; r++) {
          const int rreg = region8(16 * i + 4 * quad + r, wy, wx);
#pragma unroll
          for (int j = 0; j < 4; j++)
            if (rreg != creg[j]) s[i][j][r] -= 100.f;
        }
    }

    // softmax per row; write P into own head's swizzled slice (own-wave RAW, no barrier)
#pragma unroll
    for (int i = 0; i < 4; i++)
#pragma unroll
      for (int r = 0; r < 4; r++) {
        float mx = fmaxf(fmaxf(s[i][0][r], s[i][1][r]), fmaxf(s[i][2][r], s[i][3][r]));
#pragma unroll
        for (int off = 1; off < 16; off <<= 1) mx = fmaxf(mx, __shfl_xor(mx, off));
        float sum = 0.f;
#pragma unroll
        for (int j = 0; j < 4; j++) {
          const float p = __expf(s[i][j][r] - mx);
          s[i][j][r] = p;
          sum += p;
        }
#pragma unroll
        for (int off = 1; off < 16; off <<= 1) sum += __shfl_xor(sum, off);
        const float inv = 1.f / sum;
        const int row = 16 * i + 4 * quad + r;
#pragma unroll
        for (int j = 0; j < 4; j++)
          *p_ptr(head, row, (16 * j + c) * 2) = (bf16)(s[i][j][r] * inv);
      }

    // O = P @ V
#pragma unroll
    for (int i = 0; i < 4; i++)
#pragma unroll
      for (int tn = 0; tn < 2; tn++) o[i][tn] = fzero;
#pragma unroll
    for (int ks = 0; ks < 2; ks++) {
      bf16x8 ap[4], bv[2];
#pragma unroll
      for (int i = 0; i < 4; i++)
        ap[i] = *(const bf16x8*)p_ptr(head, 16 * i + c, ks * 64 + quad * 16);
#pragma unroll
      for (int tn = 0; tn < 2; tn++)
        bv[tn] = *(const bf16x8*)&vT_s[head * 2048 + (16 * tn + c) * 64 + ks * 32 + quad * 8];
#pragma unroll
      for (int i = 0; i < 4; i++)
#pragma unroll
        for (int tn = 0; tn < 2; tn++) o[i][tn] = MFMA16(ap[i], bv[tn], o[i][tn]);
    }
  }
  __syncthreads();   // D: all p_s reads done before ao_s overwrites the region

  // attn_out -> ao_s [64][200]
#pragma unroll
  for (int i = 0; i < 4; i++)
#pragma unroll
    for (int tn = 0; tn < 2; tn++)
#pragma unroll
      for (int r = 0; r < 4; r++)
        ao_s[(16 * i + 4 * quad + r) * 200 + waveid * 32 + 16 * tn + c] = (bf16)o[i][tn][r];
  __syncthreads();   // E

  // ---- ph4: proj GEMM + shortcut residual -> hreg (registers, fp32) ----
  float hreg[4][2][4];
  {
    f32x4 acc[4][2];
#pragma unroll
    for (int i = 0; i < 4; i++)
#pragma unroll
      for (int j = 0; j < 2; j++) acc[i][j] = fzero;
#pragma unroll
    for (int ks = 0; ks < 6; ks++) {
      bf16x8 a[4], w[2];
#pragma unroll
      for (int i = 0; i < 4; i++)
        a[i] = *(const bf16x8*)&ao_s[(16 * i + c) * 200 + ks * 32 + quad * 8];
#pragma unroll
      for (int j = 0; j < 2; j++)
        w[j] = *(const bf16x8*)(wproj +
            (size_t)(waveid * 32 + 16 * j + c) * 192 + ks * 32 + quad * 8);
#pragma unroll
      for (int i = 0; i < 4; i++)
#pragma unroll
        for (int j = 0; j < 2; j++) acc[i][j] = MFMA16(a[i], w[j], acc[i][j]);
    }
#pragma unroll
    for (int i = 0; i < 4; i++)
#pragma unroll
      for (int r = 0; r < 4; r++) {
        const int n = 16 * i + 4 * quad + r;
        const int oh = (wy * 8 + (n >> 3) + 4) & 127;
        const int ow = (wx * 8 + (n & 7) + 4) & 127;
        const float* xr = x + (size_t)(bi * 16384 + oh * 128 + ow) * 192;
#pragma unroll
        for (int j = 0; j < 2; j++) {
          const int col = waveid * 32 + 16 * j + c;
          hreg[i][j][r] = acc[i][j][r] + proj_b[col] + xr[col];
        }
      }
  }

  // ---- ph5: LN2 from registers: shuffle partials + red_s combine -> m_s ----
  // lanes of one quad (same 16-lane group) hold 32 cols of each row n=16i+4quad+r
#pragma unroll
  for (int i = 0; i < 4; i++)
#pragma unroll
    for (int r = 0; r < 4; r++) {
      float s1 = hreg[i][0][r] + hreg[i][1][r];
      float s2 = hreg[i][0][r] * hreg[i][0][r] + hreg[i][1][r] * hreg[i][1][r];
#pragma unroll
      for (int off = 1; off < 16; off <<= 1) {
        s1 += __shfl_xor(s1, off);
        s2 += __shfl_xor(s2, off);
      }
      if (c == 0) {
        const int n = 16 * i + 4 * quad + r;
        red_s[n * 16 + waveid] = s1;
        red_s[n * 16 + 8 + waveid] = s2;
      }
    }
  __syncthreads();   // F: partials visible
  {
    const int col0 = waveid * 32 + c, col1 = col0 + 16;
    const float g0 = n2g[col0], b0 = n2b[col0];
    const float g1 = n2g[col1], b1 = n2b[col1];
#pragma unroll
    for (int i = 0; i < 4; i++)
#pragma unroll
      for (int r = 0; r < 4; r++) {
        const int n = 16 * i + 4 * quad + r;
        const f32x4 lo = *(const f32x4*)&red_s[n * 16 + 0];
        const f32x4 hi = *(const f32x4*)&red_s[n * 16 + 4];
        const f32x4 qlo = *(const f32x4*)&red_s[n * 16 + 8];
        const f32x4 qhi = *(const f32x4*)&red_s[n * 16 + 12];
        const float s1 = lo[0] + lo[1] + lo[2] + lo[3] + hi[0] + hi[1];
        const float s2 = qlo[0] + qlo[1] + qlo[2] + qlo[3] + qhi[0] + qhi[1];
        const float mu = s1 * (1.f / 192.f);
        const float rinv = rsqrtf(s2 * (1.f / 192.f) - mu * mu + 1e-5f);
        m_s[n * 200 + col0] = (bf16)((hreg[i][0][r] - mu) * rinv * g0 + b0);
        m_s[n * 200 + col1] = (bf16)((hreg[i][1][r] - mu) * rinv * g1 + b1);
      }
  }
  __syncthreads();   // G: m_s visible

  // ---- ph6: MLP fc1 -> GELU -> fc2 (4 chunks of 192) ----
  f32x4 oacc[4][2];
#pragma unroll
  for (int i = 0; i < 4; i++)
#pragma unroll
    for (int j = 0; j < 2; j++) oacc[i][j] = fzero;

  for (int chunk = 0; chunk < 4; chunk++) {
    f32x4 gacc[4][2];
#pragma unroll
    for (int i = 0; i < 4; i++)
#pragma unroll
      for (int j = 0; j < 2; j++) gacc[i][j] = fzero;
#pragma unroll
    for (int ks = 0; ks < 6; ks++) {
      bf16x8 a[4], w[2];
#pragma unroll
      for (int i = 0; i < 4; i++)
        a[i] = *(const bf16x8*)&m_s[(16 * i + c) * 200 + ks * 32 + quad * 8];
#pragma unroll
      for (int j = 0; j < 2; j++)
        w[j] = *(const bf16x8*)(wfc1 +
            (size_t)(chunk * 192 + waveid * 32 + 16 * j + c) * 192 + ks * 32 + quad * 8);
#pragma unroll
      for (int i = 0; i < 4; i++)
#pragma unroll
        for (int j = 0; j < 2; j++) gacc[i][j] = MFMA16(a[i], w[j], gacc[i][j]);
    }
#pragma unroll
    for (int i = 0; i < 4; i++)
#pragma unroll
      for (int j = 0; j < 2; j++) {
        const int lcol = waveid * 32 + 16 * j + c;
        const float fb = fc1_b[chunk * 192 + lcol];
#pragma unroll
        for (int r = 0; r < 4; r++) {
          float val = gacc[i][j][r] + fb;
          val = 0.5f * val * (1.f + erff(val * 0.70710678118654752f));
          g_s[(16 * i + 4 * quad + r) * 200 + lcol] = (bf16)val;
        }
      }
    __syncthreads();
#pragma unroll
    for (int ks = 0; ks < 6; ks++) {
      bf16x8 a[4], w[2];
#pragma unroll
      for (int i = 0; i < 4; i++)
        a[i] = *(const bf16x8*)&g_s[(16 * i + c) * 200 + ks * 32 + quad * 8];
#pragma unroll
      for (int j = 0; j < 2; j++)
        w[j] = *(const bf16x8*)(wfc2 +
            (size_t)(waveid * 32 + 16 * j + c) * 768 + chunk * 192 + ks * 32 + quad * 8);
#pragma unroll
      for (int i = 0; i < 4; i++)
#pragma unroll
        for (int j = 0; j < 2; j++) oacc[i][j] = MFMA16(a[i], w[j], oacc[i][j]);
    }
    __syncthreads();
  }

  // ---- ph7: epilogue: + fc2_b + hreg, un-shift scatter, fp32 out ----
#pragma unroll
  for (int i = 0; i < 4; i++)
#pragma unroll
    for (int r = 0; r < 4; r++) {
      const int n = 16 * i + 4 * quad + r;
      const int oh = (wy * 8 + (n >> 3) + 4) & 127;
      const int ow = (wx * 8 + (n & 7) + 4) & 127;
      float* orow = out + (size_t)(bi * 16384 + oh * 128 + ow) * 192;
#pragma unroll
      for (int j = 0; j < 2; j++) {
        const int col = waveid * 32 + 16 * j + c;
        orow[col] = oacc[i][j][r] + fc2_b[col] + hreg[i][j][r];
      }
    }
}

// ---------------- launch ----------------
extern "C" void kernel_launch(void* const* d_in, const int* in_sizes, int n_in,
                              void* d_out, int out_size, void* d_ws, size_t ws_size,
                              hipStream_t stream) {
  const float* x      = (const float*)d_in[0];
  const float* n1g    = (const float*)d_in[1];
  const float* n1b    = (const float*)d_in[2];
  const float* qkv_w  = (const float*)d_in[3];
  const float* qkv_b  = (const float*)d_in[4];
  const float* proj_w = (const float*)d_in[5];
  const float* proj_b = (const float*)d_in[6];
  const float* rpb    = (const float*)d_in[7];
  const float* n2g    = (const float*)d_in[8];
  const float* n2b    = (const float*)d_in[9];
  const float* fc1_w  = (const float*)d_in[10];
  const float* fc1_b  = (const float*)d_in[11];
  const float* fc2_w  = (const float*)d_in[12];
  const float* fc2_b  = (const float*)d_in[13];

  // tiny workspace: 983,040 B total
  char* ws = (char*)d_ws;
  float* biasf = (float*)(ws);                       // 98,304 B
  bf16*  wqkv  = (bf16*)(ws + 98304);                // 221,184 B
  bf16*  wproj = (bf16*)(ws + 98304 + 221184);       // 73,728 B
  bf16*  wfc1  = (bf16*)(ws + 98304 + 221184 + 73728);            // 294,912 B
  bf16*  wfc2  = (bf16*)(ws + 98304 + 221184 + 73728 + 294912);   // 294,912 B

  prep_kernel<<<576, 256, 0, stream>>>(qkv_w, proj_w, fc1_w, fc2_w, rpb,
                                       wqkv, wproj, wfc1, wfc2, biasf);
  swin_block_kernel<<<4096, 384, 0, stream>>>(
      x, n1g, n1b, wqkv, qkv_b, wproj, proj_b, biasf,
      n2g, n2b, wfc1, fc1_b, wfc2, fc2_b, (float*)d_out);
}

// Round 2
// 1292.382 us; speedup vs baseline: 1.0982x; 1.0982x over previous
//
#include <hip/hip_runtime.h>
#include <hip/hip_bf16.h>

typedef __bf16 bf16;
typedef __bf16 bf16x4 __attribute__((ext_vector_type(4)));
typedef __bf16 bf16x8 __attribute__((ext_vector_type(8)));
typedef float f32x4 __attribute__((ext_vector_type(4)));

#define MFMA16(a, b, c) __builtin_amdgcn_mfma_f32_16x16x32_bf16(a, b, c, 0, 0, 0)

// B=16, H=W=128, C=192, WS=8, SHIFT=4, HEADS=6, N=64 -> nW=256/img, 4096 windows
#define SCALE_Q 0.17677669529663687f

// ---------------- K0: weight fp32->bf16 + rpb bias table expansion ----------------
__global__ __launch_bounds__(256) void prep_kernel(
    const float* __restrict__ qkv_w, const float* __restrict__ proj_w,
    const float* __restrict__ fc1_w, const float* __restrict__ fc2_w,
    const float* __restrict__ rpb,
    bf16* __restrict__ wqkv, bf16* __restrict__ wproj,
    bf16* __restrict__ wfc1, bf16* __restrict__ wfc2,
    float* __restrict__ bias_full) {
  const int i = blockIdx.x * 256 + threadIdx.x;
  if (i < 110592) wqkv[i] = (bf16)qkv_w[i];
  if (i < 36864)  wproj[i] = (bf16)proj_w[i];
  if (i < 147456) { wfc1[i] = (bf16)fc1_w[i]; wfc2[i] = (bf16)fc2_w[i]; }
  if (i < 24576) {
    const int head = i >> 12;           // [6][64][64]
    const int row = (i >> 6) & 63, col = i & 63;
    const int idx = ((row >> 3) - (col >> 3) + 7) * 15 + ((row & 7) - (col & 7) + 7);
    bias_full[i] = rpb[idx * 6 + head];
  }
}

__device__ __forceinline__ int region8(int tok, int wy, int wx) {
  const int gh = wy * 8 + (tok >> 3), gw = wx * 8 + (tok & 7);
  const int rs = (gh < 120) ? 0 : ((gh < 124) ? 1 : 2);
  const int cs = (gw < 120) ? 0 : ((gw < 124) ? 1 : 2);
  return rs * 3 + cs;
}

// ---------------- K1: whole Swin block, 1 window per 384-thread block ----------------
// LDS map (bytes), phase-aliased; high water 76800 -> 2 blocks/CU:
//   [0,25600)      a_s   bf16 [64][200]         ph1-2a
//   [0,24576)      q_s   bf16 [6][64][32]       ph2b-3a (over a_s, barrier A)
//   [24576,49152)  k_s   bf16 [6][64][32]       ph2b-3a
//   [49152,76800)  vT_s  bf16 [6][32][72]       ph2b-3  (pitch 72: 2-way banks)
//   [0,49152)      p_s   bf16 [6][64][64] XOR   ph3b (over q+k, barrier C)
//   [0,25600)      ao_s  bf16 [64][200]         ph4 (over p low, barriers D/E)
//   [0,25600)      m_s   bf16 [64][200]         ph5b-6 (over ao, barrier F)
//   [25600,51200)  g_s   bf16 [64][200]         ph6
//   [51200,55296)  red_s f32  [64][16]          ph5 (over dead vT)
// residual h: written to out[] in ph4 (same thread reads it back in ph7);
// registers only carry h across one barrier (ph4->ph5b), keeping VGPR ~<130.
__global__ __launch_bounds__(384, 1) void swin_block_kernel(
    const float* __restrict__ x,
    const float* __restrict__ n1g, const float* __restrict__ n1b,
    const bf16* __restrict__ wqkv, const float* __restrict__ qkv_b,
    const bf16* __restrict__ wproj, const float* __restrict__ proj_b,
    const float* __restrict__ bias_full,
    const float* __restrict__ n2g, const float* __restrict__ n2b,
    const bf16* __restrict__ wfc1, const float* __restrict__ fc1_b,
    const bf16* __restrict__ wfc2, const float* __restrict__ fc2_b,
    float* __restrict__ out) {
  __shared__ __align__(16) char smem[76800];
  bf16*  a_s  = (bf16*)(smem);
  bf16*  q_s  = (bf16*)(smem);
  bf16*  k_s  = (bf16*)(smem + 24576);
  bf16*  vT_s = (bf16*)(smem + 49152);   // [6][32][72]
  bf16*  ao_s = (bf16*)(smem);
  bf16*  m_s  = (bf16*)(smem);
  bf16*  g_s  = (bf16*)(smem + 25600);
  float* red_s = (float*)(smem + 51200);

  const int lane = threadIdx.x & 63, waveid = threadIdx.x >> 6;
  const int c = lane & 15, quad = lane >> 4;
  const int window = blockIdx.x;
  const int bi = window >> 8, w_in = window & 255;
  const int wy = w_in >> 4, wx = w_in & 15;
  const f32x4 fzero = {0.f, 0.f, 0.f, 0.f};

  // swizzled P accessor: [head][row][col] bf16, pitch 64, byte ^= (row&7)<<4
  auto p_ptr = [&](int head, int row, int colbyte) -> bf16* {
    int off = (row << 7) + colbyte;
    off ^= (row & 7) << 4;
    return (bf16*)(smem + (head << 13) + off);
  };

  // ---- ph1: LN1 + roll(-4,-4) gather -> a_s ----
  for (int it = 0; it < 11; it++) {
    const int n = waveid * 11 + it;
    if (n < 64) {
      const int oh = (wy * 8 + (n >> 3) + 4) & 127;
      const int ow = (wx * 8 + (n & 7) + 4) & 127;
      const float* xr = x + (size_t)(bi * 16384 + oh * 128 + ow) * 192;
      float v0 = xr[lane], v1 = xr[lane + 64], v2 = xr[lane + 128];
      float s = v0 + v1 + v2;
      float s2 = v0 * v0 + v1 * v1 + v2 * v2;
#pragma unroll
      for (int off = 1; off < 64; off <<= 1) {
        s += __shfl_xor(s, off);
        s2 += __shfl_xor(s2, off);
      }
      const float mu = s * (1.f / 192.f);
      const float rinv = rsqrtf(s2 * (1.f / 192.f) - mu * mu + 1e-5f);
      a_s[n * 200 + lane]       = (bf16)((v0 - mu) * rinv * n1g[lane]       + n1b[lane]);
      a_s[n * 200 + lane + 64]  = (bf16)((v1 - mu) * rinv * n1g[lane + 64]  + n1b[lane + 64]);
      a_s[n * 200 + lane + 128] = (bf16)((v2 - mu) * rinv * n1g[lane + 128] + n1b[lane + 128]);
    }
  }
  __syncthreads();

  // ---- ph2: qkv GEMM (wave covers 96 cols = one tensor x one head pair) ----
  // Accumulate fully in regs; barrier; then scatter q/k/vT OVER the a_s region.
  {
    f32x4 acc[4][6];
#pragma unroll
    for (int i = 0; i < 4; i++)
#pragma unroll
      for (int j = 0; j < 6; j++) acc[i][j] = fzero;
#pragma unroll
    for (int ks = 0; ks < 6; ks++) {
      bf16x8 a[4], w[6];
#pragma unroll
      for (int i = 0; i < 4; i++)
        a[i] = *(const bf16x8*)&a_s[(16 * i + c) * 200 + ks * 32 + quad * 8];
#pragma unroll
      for (int j = 0; j < 6; j++)
        w[j] = *(const bf16x8*)(wqkv +
            (size_t)(waveid * 96 + 16 * j + c) * 192 + ks * 32 + quad * 8);
#pragma unroll
      for (int i = 0; i < 4; i++)
#pragma unroll
        for (int j = 0; j < 6; j++) acc[i][j] = MFMA16(a[i], w[j], acc[i][j]);
    }
    __syncthreads();   // A: all a_s reads complete before q/k overwrite it
    const int which = waveid >> 1;   // 0=q 1=k 2=v (wave-uniform)
    if (which == 2) {
      // vT[head][d][n] pitch 72; r-values are n-consecutive -> ds_write_b64
#pragma unroll
      for (int j = 0; j < 6; j++) {
        const int col = waveid * 96 + 16 * j + c;
        const int sub = col - 384;
        const int head = sub >> 5, d = sub & 31;
        const float bias = qkv_b[col];
#pragma unroll
        for (int i = 0; i < 4; i++) {
          bf16x4 pk;
#pragma unroll
          for (int r = 0; r < 4; r++) pk[r] = (bf16)(acc[i][j][r] + bias);
          *(bf16x4*)&vT_s[head * 2304 + d * 72 + 16 * i + 4 * quad] = pk;
        }
      }
    } else {
#pragma unroll
      for (int j = 0; j < 6; j++) {
        const int col = waveid * 96 + 16 * j + c;
        const int sub = col - which * 192;
        const int head = sub >> 5, d = sub & 31;
        const float bias = qkv_b[col];
#pragma unroll
        for (int i = 0; i < 4; i++)
#pragma unroll
          for (int r = 0; r < 4; r++) {
            const int n = 16 * i + 4 * quad + r;
            const float val = acc[i][j][r] + bias;
            if (which == 0) q_s[head * 2048 + n * 32 + d] = (bf16)(val * SCALE_Q);
            else            k_s[head * 2048 + n * 32 + d] = (bf16)val;
          }
      }
    }
  }
  __syncthreads();   // B: q/k/vT visible to all waves

  // ---- ph3: attention, wave = head ----
  f32x4 o[4][2];
  {
    const int head = waveid;
    bf16x8 aq[4], bk[4];
#pragma unroll
    for (int i = 0; i < 4; i++)
      aq[i] = *(const bf16x8*)&q_s[head * 2048 + (16 * i + c) * 32 + quad * 8];
#pragma unroll
    for (int j = 0; j < 4; j++)
      bk[j] = *(const bf16x8*)&k_s[head * 2048 + (16 * j + c) * 32 + quad * 8];
    __syncthreads();   // C: all q/k fragment loads landed; P may overwrite q/k

    f32x4 s[4][4];
#pragma unroll
    for (int i = 0; i < 4; i++)
#pragma unroll
      for (int j = 0; j < 4; j++) s[i][j] = fzero;
#pragma unroll
    for (int i = 0; i < 4; i++)
#pragma unroll
      for (int j = 0; j < 4; j++) s[i][j] = MFMA16(aq[i], bk[j], s[i][j]);

    const float* bfp = bias_full + head * 4096;
#pragma unroll
    for (int i = 0; i < 4; i++)
#pragma unroll
      for (int r = 0; r < 4; r++) {
        const int row = 16 * i + 4 * quad + r;
#pragma unroll
        for (int j = 0; j < 4; j++) s[i][j][r] += bfp[row * 64 + 16 * j + c];
      }

    if (wy == 15 || wx == 15) {
      int creg[4];
#pragma unroll
      for (int j = 0; j < 4; j++) creg[j] = region8(16 * j + c, wy, wx);
#pragma unroll
      for (int i = 0; i < 4; i++)
#pragma unroll
        for (int r = 0; r < 4; r++) {
          const int rreg = region8(16 * i + 4 * quad + r, wy, wx);
#pragma unroll
          for (int j = 0; j < 4; j++)
            if (rreg != creg[j]) s[i][j][r] -= 100.f;
        }
    }

    // softmax per row; write P into own head's swizzled slice (own-wave RAW, no barrier)
#pragma unroll
    for (int i = 0; i < 4; i++)
#pragma unroll
      for (int r = 0; r < 4; r++) {
        float mx = fmaxf(fmaxf(s[i][0][r], s[i][1][r]), fmaxf(s[i][2][r], s[i][3][r]));
#pragma unroll
        for (int off = 1; off < 16; off <<= 1) mx = fmaxf(mx, __shfl_xor(mx, off));
        float sum = 0.f;
#pragma unroll
        for (int j = 0; j < 4; j++) {
          const float p = __expf(s[i][j][r] - mx);
          s[i][j][r] = p;
          sum += p;
        }
#pragma unroll
        for (int off = 1; off < 16; off <<= 1) sum += __shfl_xor(sum, off);
        const float inv = 1.f / sum;
        const int row = 16 * i + 4 * quad + r;
#pragma unroll
        for (int j = 0; j < 4; j++)
          *p_ptr(head, row, (16 * j + c) * 2) = (bf16)(s[i][j][r] * inv);
      }

    // O = P @ V
#pragma unroll
    for (int i = 0; i < 4; i++)
#pragma unroll
      for (int tn = 0; tn < 2; tn++) o[i][tn] = fzero;
#pragma unroll
    for (int ks = 0; ks < 2; ks++) {
      bf16x8 ap[4], bv[2];
#pragma unroll
      for (int i = 0; i < 4; i++)
        ap[i] = *(const bf16x8*)p_ptr(head, 16 * i + c, ks * 64 + quad * 16);
#pragma unroll
      for (int tn = 0; tn < 2; tn++)
        bv[tn] = *(const bf16x8*)&vT_s[head * 2304 + (16 * tn + c) * 72 + ks * 32 + quad * 8];
#pragma unroll
      for (int i = 0; i < 4; i++)
#pragma unroll
        for (int tn = 0; tn < 2; tn++) o[i][tn] = MFMA16(ap[i], bv[tn], o[i][tn]);
    }
  }
  __syncthreads();   // D: all p_s reads done before ao_s overwrites the region

  // attn_out -> ao_s [64][200]
#pragma unroll
  for (int i = 0; i < 4; i++)
#pragma unroll
    for (int tn = 0; tn < 2; tn++)
#pragma unroll
      for (int r = 0; r < 4; r++)
        ao_s[(16 * i + 4 * quad + r) * 200 + waveid * 32 + 16 * tn + c] = (bf16)o[i][tn][r];
  __syncthreads();   // E

  // ---- ph4: proj GEMM + shortcut residual; h -> out (global) + LN2 partials ----
  float hv[4][2][4];
  {
    f32x4 acc[4][2];
#pragma unroll
    for (int i = 0; i < 4; i++)
#pragma unroll
      for (int j = 0; j < 2; j++) acc[i][j] = fzero;
#pragma unroll
    for (int ks = 0; ks < 6; ks++) {
      bf16x8 a[4], w[2];
#pragma unroll
      for (int i = 0; i < 4; i++)
        a[i] = *(const bf16x8*)&ao_s[(16 * i + c) * 200 + ks * 32 + quad * 8];
#pragma unroll
      for (int j = 0; j < 2; j++)
        w[j] = *(const bf16x8*)(wproj +
            (size_t)(waveid * 32 + 16 * j + c) * 192 + ks * 32 + quad * 8);
#pragma unroll
      for (int i = 0; i < 4; i++)
#pragma unroll
        for (int j = 0; j < 2; j++) acc[i][j] = MFMA16(a[i], w[j], acc[i][j]);
    }
#pragma unroll
    for (int i = 0; i < 4; i++)
#pragma unroll
      for (int r = 0; r < 4; r++) {
        const int n = 16 * i + 4 * quad + r;
        const int oh = (wy * 8 + (n >> 3) + 4) & 127;
        const int ow = (wx * 8 + (n & 7) + 4) & 127;
        const size_t base = (size_t)(bi * 16384 + oh * 128 + ow) * 192;
        const float* xr = x + base;
        float* orow = out + base;
#pragma unroll
        for (int j = 0; j < 2; j++) {
          const int col = waveid * 32 + 16 * j + c;
          const float h = acc[i][j][r] + proj_b[col] + xr[col];
          hv[i][j][r] = h;
          orow[col] = h;   // stash residual; same thread reads it back in ph7
        }
      }
  }

  // ---- ph5a: LN2 partial sums (quad-shuffle over this wave's 32 cols) ----
#pragma unroll
  for (int i = 0; i < 4; i++)
#pragma unroll
    for (int r = 0; r < 4; r++) {
      float s1 = hv[i][0][r] + hv[i][1][r];
      float s2 = hv[i][0][r] * hv[i][0][r] + hv[i][1][r] * hv[i][1][r];
#pragma unroll
      for (int off = 1; off < 16; off <<= 1) {
        s1 += __shfl_xor(s1, off);
        s2 += __shfl_xor(s2, off);
      }
      if (c == 0) {
        const int n = 16 * i + 4 * quad + r;
        red_s[n * 16 + waveid] = s1;
        red_s[n * 16 + 8 + waveid] = s2;
      }
    }
  __syncthreads();   // F: partials visible; ao reads done -> m_s may overwrite

  // ---- ph5b: LN2 normalize -> m_s ----
  {
    const int col0 = waveid * 32 + c, col1 = col0 + 16;
    const float g0 = n2g[col0], b0 = n2b[col0];
    const float g1 = n2g[col1], b1 = n2b[col1];
#pragma unroll
    for (int i = 0; i < 4; i++)
#pragma unroll
      for (int r = 0; r < 4; r++) {
        const int n = 16 * i + 4 * quad + r;
        const f32x4 lo = *(const f32x4*)&red_s[n * 16 + 0];
        const f32x4 hi = *(const f32x4*)&red_s[n * 16 + 4];
        const f32x4 qlo = *(const f32x4*)&red_s[n * 16 + 8];
        const f32x4 qhi = *(const f32x4*)&red_s[n * 16 + 12];
        const float s1 = lo[0] + lo[1] + lo[2] + lo[3] + hi[0] + hi[1];
        const float s2 = qlo[0] + qlo[1] + qlo[2] + qlo[3] + qhi[0] + qhi[1];
        const float mu = s1 * (1.f / 192.f);
        const float rinv = rsqrtf(s2 * (1.f / 192.f) - mu * mu + 1e-5f);
        m_s[n * 200 + col0] = (bf16)((hv[i][0][r] - mu) * rinv * g0 + b0);
        m_s[n * 200 + col1] = (bf16)((hv[i][1][r] - mu) * rinv * g1 + b1);
      }
  }
  __syncthreads();   // G: m_s visible

  // ---- ph6: MLP fc1 -> GELU -> fc2 (4 chunks of 192) ----
  f32x4 oacc[4][2];
#pragma unroll
  for (int i = 0; i < 4; i++)
#pragma unroll
    for (int j = 0; j < 2; j++) oacc[i][j] = fzero;

  for (int chunk = 0; chunk < 4; chunk++) {
    f32x4 gacc[4][2];
#pragma unroll
    for (int i = 0; i < 4; i++)
#pragma unroll
      for (int j = 0; j < 2; j++) gacc[i][j] = fzero;
#pragma unroll
    for (int ks = 0; ks < 6; ks++) {
      bf16x8 a[4], w[2];
#pragma unroll
      for (int i = 0; i < 4; i++)
        a[i] = *(const bf16x8*)&m_s[(16 * i + c) * 200 + ks * 32 + quad * 8];
#pragma unroll
      for (int j = 0; j < 2; j++)
        w[j] = *(const bf16x8*)(wfc1 +
            (size_t)(chunk * 192 + waveid * 32 + 16 * j + c) * 192 + ks * 32 + quad * 8);
#pragma unroll
      for (int i = 0; i < 4; i++)
#pragma unroll
        for (int j = 0; j < 2; j++) gacc[i][j] = MFMA16(a[i], w[j], gacc[i][j]);
    }
#pragma unroll
    for (int i = 0; i < 4; i++)
#pragma unroll
      for (int j = 0; j < 2; j++) {
        const int lcol = waveid * 32 + 16 * j + c;
        const float fb = fc1_b[chunk * 192 + lcol];
#pragma unroll
        for (int r = 0; r < 4; r++) {
          float val = gacc[i][j][r] + fb;
          val = 0.5f * val * (1.f + erff(val * 0.70710678118654752f));
          g_s[(16 * i + 4 * quad + r) * 200 + lcol] = (bf16)val;
        }
      }
    __syncthreads();
#pragma unroll
    for (int ks = 0; ks < 6; ks++) {
      bf16x8 a[4], w[2];
#pragma unroll
      for (int i = 0; i < 4; i++)
        a[i] = *(const bf16x8*)&g_s[(16 * i + c) * 200 + ks * 32 + quad * 8];
#pragma unroll
      for (int j = 0; j < 2; j++)
        w[j] = *(const bf16x8*)(wfc2 +
            (size_t)(waveid * 32 + 16 * j + c) * 768 + chunk * 192 + ks * 32 + quad * 8);
#pragma unroll
      for (int i = 0; i < 4; i++)
#pragma unroll
        for (int j = 0; j < 2; j++) oacc[i][j] = MFMA16(a[i], w[j], oacc[i][j]);
    }
    __syncthreads();
  }

  // ---- ph7: epilogue: + fc2_b + h (read back from out), fp32 out ----
#pragma unroll
  for (int i = 0; i < 4; i++)
#pragma unroll
    for (int r = 0; r < 4; r++) {
      const int n = 16 * i + 4 * quad + r;
      const int oh = (wy * 8 + (n >> 3) + 4) & 127;
      const int ow = (wx * 8 + (n & 7) + 4) & 127;
      float* orow = out + (size_t)(bi * 16384 + oh * 128 + ow) * 192;
#pragma unroll
      for (int j = 0; j < 2; j++) {
        const int col = waveid * 32 + 16 * j + c;
        const float h = orow[col];
        orow[col] = oacc[i][j][r] + fc2_b[col] + h;
      }
    }
}

// ---------------- launch ----------------
extern "C" void kernel_launch(void* const* d_in, const int* in_sizes, int n_in,
                              void* d_out, int out_size, void* d_ws, size_t ws_size,
                              hipStream_t stream) {
  const float* x      = (const float*)d_in[0];
  const float* n1g    = (const float*)d_in[1];
  const float* n1b    = (const float*)d_in[2];
  const float* qkv_w  = (const float*)d_in[3];
  const float* qkv_b  = (const float*)d_in[4];
  const float* proj_w = (const float*)d_in[5];
  const float* proj_b = (const float*)d_in[6];
  const float* rpb    = (const float*)d_in[7];
  const float* n2g    = (const float*)d_in[8];
  const float* n2b    = (const float*)d_in[9];
  const float* fc1_w  = (const float*)d_in[10];
  const float* fc1_b  = (const float*)d_in[11];
  const float* fc2_w  = (const float*)d_in[12];
  const float* fc2_b  = (const float*)d_in[13];

  // tiny workspace: 983,040 B total
  char* ws = (char*)d_ws;
  float* biasf = (float*)(ws);                       // 98,304 B
  bf16*  wqkv  = (bf16*)(ws + 98304);                // 221,184 B
  bf16*  wproj = (bf16*)(ws + 98304 + 221184);       // 73,728 B
  bf16*  wfc1  = (bf16*)(ws + 98304 + 221184 + 73728);            // 294,912 B
  bf16*  wfc2  = (bf16*)(ws + 98304 + 221184 + 73728 + 294912);   // 294,912 B

  prep_kernel<<<576, 256, 0, stream>>>(qkv_w, proj_w, fc1_w, fc2_w, rpb,
                                       wqkv, wproj, wfc1, wfc2, biasf);
  swin_block_kernel<<<4096, 384, 0, stream>>>(
      x, n1g, n1b, wqkv, qkv_b, wproj, proj_b, biasf,
      n2g, n2b, wfc1, fc1_b, wfc2, fc2_b, (float*)d_out);
}

// Round 3
// 1271.031 us; speedup vs baseline: 1.1167x; 1.0168x over previous
//
#include <hip/hip_runtime.h>
#include <hip/hip_bf16.h>

typedef __bf16 bf16;
typedef __bf16 bf16x4 __attribute__((ext_vector_type(4)));
typedef __bf16 bf16x8 __attribute__((ext_vector_type(8)));
typedef float f32x4 __attribute__((ext_vector_type(4)));

#define MFMA16(a, b, c) __builtin_amdgcn_mfma_f32_16x16x32_bf16(a, b, c, 0, 0, 0)

// B=16, H=W=128, C=192, WS=8, SHIFT=4, HEADS=6, N=64 -> nW=256/img, 4096 windows
#define SCALE_Q 0.17677669529663687f

// ---------------- K0: weight fp32->bf16 + rpb bias table expansion ----------------
__global__ __launch_bounds__(256) void prep_kernel(
    const float* __restrict__ qkv_w, const float* __restrict__ proj_w,
    const float* __restrict__ fc1_w, const float* __restrict__ fc2_w,
    const float* __restrict__ rpb,
    bf16* __restrict__ wqkv, bf16* __restrict__ wproj,
    bf16* __restrict__ wfc1, bf16* __restrict__ wfc2,
    float* __restrict__ bias_full) {
  const int i = blockIdx.x * 256 + threadIdx.x;
  if (i < 110592) wqkv[i] = (bf16)qkv_w[i];
  if (i < 36864)  wproj[i] = (bf16)proj_w[i];
  if (i < 147456) { wfc1[i] = (bf16)fc1_w[i]; wfc2[i] = (bf16)fc2_w[i]; }
  if (i < 24576) {
    const int head = i >> 12;           // [6][64][64]
    const int row = (i >> 6) & 63, col = i & 63;
    const int idx = ((row >> 3) - (col >> 3) + 7) * 15 + ((row & 7) - (col & 7) + 7);
    bias_full[i] = rpb[idx * 6 + head];
  }
}

__device__ __forceinline__ int region8(int tok, int wy, int wx) {
  const int gh = wy * 8 + (tok >> 3), gw = wx * 8 + (tok & 7);
  const int rs = (gh < 120) ? 0 : ((gh < 124) ? 1 : 2);
  const int cs = (gw < 120) ? 0 : ((gw < 124) ? 1 : 2);
  return rs * 3 + cs;
}

// ---------------- K1: whole Swin block, 1 window per 384-thread block ----------------
// LDS map (bytes), phase-aliased; high water 76800 -> target 2 blocks/CU:
//   [0,25600)      a_s   bf16 [64][200]         ph1-2
//   [0,27648)      vT_s  bf16 [6][32][72]       ph2c-3 (over a_s, barrier A)
//   [27648,52224)  q_s   bf16 [6][64][32]       ph2a-3a
//   [52224,76800)  k_s   bf16 [6][64][32]       ph2b-3a
//   [27648,76800)  p_s   bf16 [6][64][64] XOR   ph3b (over q+k, barrier C)
//   [0,25600)      ao_s  bf16 [64][200]         ph4 (over vT, barriers D/E)
//   [0,25600)      m_s   bf16 [64][200]         ph5b-6 (over ao, barrier F)
//   [25600,51200)  g_s   bf16 [64][200]         ph6
//   [51200,55296)  red_s f32  [64][16]          ph5 (inside dead p region)
// Register budget: __launch_bounds__(384,3) -> 168 total/wave (3 waves/SIMD =
// 2 blocks/CU). qkv GEMM runs as 3 passes (q,k,v) so peak acc = 32 regs, not 96;
// worst phase (attention) ~= 64 acc + ~75 arch < 168.
// residual h: stashed to out[] in ph4, same thread reads it back in ph7.
__global__ __launch_bounds__(384, 3) void swin_block_kernel(
    const float* __restrict__ x,
    const float* __restrict__ n1g, const float* __restrict__ n1b,
    const bf16* __restrict__ wqkv, const float* __restrict__ qkv_b,
    const bf16* __restrict__ wproj, const float* __restrict__ proj_b,
    const float* __restrict__ bias_full,
    const float* __restrict__ n2g, const float* __restrict__ n2b,
    const bf16* __restrict__ wfc1, const float* __restrict__ fc1_b,
    const bf16* __restrict__ wfc2, const float* __restrict__ fc2_b,
    float* __restrict__ out) {
  __shared__ __align__(16) char smem[76800];
  bf16*  a_s  = (bf16*)(smem);
  bf16*  vT_s = (bf16*)(smem);           // [6][32][72] after barrier A
  bf16*  q_s  = (bf16*)(smem + 27648);   // [6][64][32]
  bf16*  k_s  = (bf16*)(smem + 52224);   // [6][64][32]
  bf16*  ao_s = (bf16*)(smem);
  bf16*  m_s  = (bf16*)(smem);
  bf16*  g_s  = (bf16*)(smem + 25600);
  float* red_s = (float*)(smem + 51200);

  const int lane = threadIdx.x & 63, waveid = threadIdx.x >> 6;
  const int c = lane & 15, quad = lane >> 4;
  const int window = blockIdx.x;
  const int bi = window >> 8, w_in = window & 255;
  const int wy = w_in >> 4, wx = w_in & 15;
  const f32x4 fzero = {0.f, 0.f, 0.f, 0.f};

  // swizzled P accessor: [head][row][col] bf16, pitch 64, byte ^= (row&7)<<4
  auto p_ptr = [&](int head, int row, int colbyte) -> bf16* {
    int off = (row << 7) + colbyte;
    off ^= (row & 7) << 4;
    return (bf16*)(smem + 27648 + (head << 13) + off);
  };

  // ---- ph1: LN1 + roll(-4,-4) gather -> a_s ----
  for (int it = 0; it < 11; it++) {
    const int n = waveid * 11 + it;
    if (n < 64) {
      const int oh = (wy * 8 + (n >> 3) + 4) & 127;
      const int ow = (wx * 8 + (n & 7) + 4) & 127;
      const float* xr = x + (size_t)(bi * 16384 + oh * 128 + ow) * 192;
      float v0 = xr[lane], v1 = xr[lane + 64], v2 = xr[lane + 128];
      float s = v0 + v1 + v2;
      float s2 = v0 * v0 + v1 * v1 + v2 * v2;
#pragma unroll
      for (int off = 1; off < 64; off <<= 1) {
        s += __shfl_xor(s, off);
        s2 += __shfl_xor(s2, off);
      }
      const float mu = s * (1.f / 192.f);
      const float rinv = rsqrtf(s2 * (1.f / 192.f) - mu * mu + 1e-5f);
      a_s[n * 200 + lane]       = (bf16)((v0 - mu) * rinv * n1g[lane]       + n1b[lane]);
      a_s[n * 200 + lane + 64]  = (bf16)((v1 - mu) * rinv * n1g[lane + 64]  + n1b[lane + 64]);
      a_s[n * 200 + lane + 128] = (bf16)((v2 - mu) * rinv * n1g[lane + 128] + n1b[lane + 128]);
    }
  }
  __syncthreads();

  // ---- ph2: qkv GEMM, 3 passes (q,k,v) x 32 cols/wave; wave == head ----
  // Pass q/k scatter to non-aliased q_s/k_s (no barrier). Pass v barriers (A)
  // then overwrites a_s with vT. Peak live acc = 32 regs.
  {
    const int head = waveid;
#pragma unroll
    for (int which = 0; which < 3; which++) {
      f32x4 acc[4][2];
#pragma unroll
      for (int i = 0; i < 4; i++)
#pragma unroll
        for (int j = 0; j < 2; j++) acc[i][j] = fzero;
#pragma unroll
      for (int ks = 0; ks < 6; ks++) {
        bf16x8 a[4], w[2];
#pragma unroll
        for (int i = 0; i < 4; i++)
          a[i] = *(const bf16x8*)&a_s[(16 * i + c) * 200 + ks * 32 + quad * 8];
#pragma unroll
        for (int j = 0; j < 2; j++)
          w[j] = *(const bf16x8*)(wqkv +
              (size_t)(which * 192 + head * 32 + 16 * j + c) * 192 + ks * 32 + quad * 8);
#pragma unroll
        for (int i = 0; i < 4; i++)
#pragma unroll
          for (int j = 0; j < 2; j++) acc[i][j] = MFMA16(a[i], w[j], acc[i][j]);
      }
      if (which == 2) {
        __syncthreads();   // A: all a_s reads (all passes, all waves) done
#pragma unroll
        for (int j = 0; j < 2; j++) {
          const int d = 16 * j + c;
          const float bias = qkv_b[384 + head * 32 + d];
#pragma unroll
          for (int i = 0; i < 4; i++) {
            bf16x4 pk;
#pragma unroll
            for (int r = 0; r < 4; r++) pk[r] = (bf16)(acc[i][j][r] + bias);
            *(bf16x4*)&vT_s[head * 2304 + d * 72 + 16 * i + 4 * quad] = pk;
          }
        }
      } else {
        bf16* dst = (which == 0) ? q_s : k_s;
        const float mul = (which == 0) ? SCALE_Q : 1.f;
#pragma unroll
        for (int j = 0; j < 2; j++) {
          const int d = 16 * j + c;
          const float bias = qkv_b[which * 192 + head * 32 + d];
#pragma unroll
          for (int i = 0; i < 4; i++)
#pragma unroll
            for (int r = 0; r < 4; r++) {
              const int n = 16 * i + 4 * quad + r;
              dst[head * 2048 + n * 32 + d] = (bf16)((acc[i][j][r] + bias) * mul);
            }
        }
      }
    }
  }
  __syncthreads();   // B: q/k/vT visible to all waves

  // ---- ph3: attention, wave = head ----
  f32x4 o[4][2];
  {
    const int head = waveid;
    bf16x8 aq[4], bk[4];
#pragma unroll
    for (int i = 0; i < 4; i++)
      aq[i] = *(const bf16x8*)&q_s[head * 2048 + (16 * i + c) * 32 + quad * 8];
#pragma unroll
    for (int j = 0; j < 4; j++)
      bk[j] = *(const bf16x8*)&k_s[head * 2048 + (16 * j + c) * 32 + quad * 8];
    __syncthreads();   // C: all q/k fragment loads landed; P may overwrite q/k

    f32x4 s[4][4];
#pragma unroll
    for (int i = 0; i < 4; i++)
#pragma unroll
      for (int j = 0; j < 4; j++) s[i][j] = fzero;
#pragma unroll
    for (int i = 0; i < 4; i++)
#pragma unroll
      for (int j = 0; j < 4; j++) s[i][j] = MFMA16(aq[i], bk[j], s[i][j]);

    const float* bfp = bias_full + head * 4096;
#pragma unroll
    for (int i = 0; i < 4; i++)
#pragma unroll
      for (int r = 0; r < 4; r++) {
        const int row = 16 * i + 4 * quad + r;
#pragma unroll
        for (int j = 0; j < 4; j++) s[i][j][r] += bfp[row * 64 + 16 * j + c];
      }

    if (wy == 15 || wx == 15) {
      int creg[4];
#pragma unroll
      for (int j = 0; j < 4; j++) creg[j] = region8(16 * j + c, wy, wx);
#pragma unroll
      for (int i = 0; i < 4; i++)
#pragma unroll
        for (int r = 0; r < 4; r++) {
          const int rreg = region8(16 * i + 4 * quad + r, wy, wx);
#pragma unroll
          for (int j = 0; j < 4; j++)
            if (rreg != creg[j]) s[i][j][r] -= 100.f;
        }
    }

    // softmax per row; write P into own head's swizzled slice (own-wave RAW, no barrier)
#pragma unroll
    for (int i = 0; i < 4; i++)
#pragma unroll
      for (int r = 0; r < 4; r++) {
        float mx = fmaxf(fmaxf(s[i][0][r], s[i][1][r]), fmaxf(s[i][2][r], s[i][3][r]));
#pragma unroll
        for (int off = 1; off < 16; off <<= 1) mx = fmaxf(mx, __shfl_xor(mx, off));
        float sum = 0.f;
#pragma unroll
        for (int j = 0; j < 4; j++) {
          const float p = __expf(s[i][j][r] - mx);
          s[i][j][r] = p;
          sum += p;
        }
#pragma unroll
        for (int off = 1; off < 16; off <<= 1) sum += __shfl_xor(sum, off);
        const float inv = 1.f / sum;
        const int row = 16 * i + 4 * quad + r;
#pragma unroll
        for (int j = 0; j < 4; j++)
          *p_ptr(head, row, (16 * j + c) * 2) = (bf16)(s[i][j][r] * inv);
      }

    // O = P @ V
#pragma unroll
    for (int i = 0; i < 4; i++)
#pragma unroll
      for (int tn = 0; tn < 2; tn++) o[i][tn] = fzero;
#pragma unroll
    for (int ks = 0; ks < 2; ks++) {
      bf16x8 ap[4], bv[2];
#pragma unroll
      for (int i = 0; i < 4; i++)
        ap[i] = *(const bf16x8*)p_ptr(head, 16 * i + c, ks * 64 + quad * 16);
#pragma unroll
      for (int tn = 0; tn < 2; tn++)
        bv[tn] = *(const bf16x8*)&vT_s[head * 2304 + (16 * tn + c) * 72 + ks * 32 + quad * 8];
#pragma unroll
      for (int i = 0; i < 4; i++)
#pragma unroll
        for (int tn = 0; tn < 2; tn++) o[i][tn] = MFMA16(ap[i], bv[tn], o[i][tn]);
    }
  }
  __syncthreads();   // D: all p_s/vT reads done before ao_s overwrites [0,25600)

  // attn_out -> ao_s [64][200]
#pragma unroll
  for (int i = 0; i < 4; i++)
#pragma unroll
    for (int tn = 0; tn < 2; tn++)
#pragma unroll
      for (int r = 0; r < 4; r++)
        ao_s[(16 * i + 4 * quad + r) * 200 + waveid * 32 + 16 * tn + c] = (bf16)o[i][tn][r];
  __syncthreads();   // E

  // ---- ph4: proj GEMM + shortcut residual; h -> out (global) ----
  float hv[4][2][4];
  {
    f32x4 acc[4][2];
#pragma unroll
    for (int i = 0; i < 4; i++)
#pragma unroll
      for (int j = 0; j < 2; j++) acc[i][j] = fzero;
#pragma unroll
    for (int ks = 0; ks < 6; ks++) {
      bf16x8 a[4], w[2];
#pragma unroll
      for (int i = 0; i < 4; i++)
        a[i] = *(const bf16x8*)&ao_s[(16 * i + c) * 200 + ks * 32 + quad * 8];
#pragma unroll
      for (int j = 0; j < 2; j++)
        w[j] = *(const bf16x8*)(wproj +
            (size_t)(waveid * 32 + 16 * j + c) * 192 + ks * 32 + quad * 8);
#pragma unroll
      for (int i = 0; i < 4; i++)
#pragma unroll
        for (int j = 0; j < 2; j++) acc[i][j] = MFMA16(a[i], w[j], acc[i][j]);
    }
#pragma unroll
    for (int i = 0; i < 4; i++)
#pragma unroll
      for (int r = 0; r < 4; r++) {
        const int n = 16 * i + 4 * quad + r;
        const int oh = (wy * 8 + (n >> 3) + 4) & 127;
        const int ow = (wx * 8 + (n & 7) + 4) & 127;
        const size_t base = (size_t)(bi * 16384 + oh * 128 + ow) * 192;
        const float* xr = x + base;
        float* orow = out + base;
#pragma unroll
        for (int j = 0; j < 2; j++) {
          const int col = waveid * 32 + 16 * j + c;
          const float h = acc[i][j][r] + proj_b[col] + xr[col];
          hv[i][j][r] = h;
          orow[col] = h;   // stash residual; same thread reads it back in ph7
        }
      }
  }

  // ---- ph5a: LN2 partial sums (quad-shuffle over this wave's 32 cols) ----
#pragma unroll
  for (int i = 0; i < 4; i++)
#pragma unroll
    for (int r = 0; r < 4; r++) {
      float s1 = hv[i][0][r] + hv[i][1][r];
      float s2 = hv[i][0][r] * hv[i][0][r] + hv[i][1][r] * hv[i][1][r];
#pragma unroll
      for (int off = 1; off < 16; off <<= 1) {
        s1 += __shfl_xor(s1, off);
        s2 += __shfl_xor(s2, off);
      }
      if (c == 0) {
        const int n = 16 * i + 4 * quad + r;
        red_s[n * 16 + waveid] = s1;
        red_s[n * 16 + 8 + waveid] = s2;
      }
    }
  __syncthreads();   // F: partials visible; ao reads done -> m_s may overwrite

  // ---- ph5b: LN2 normalize -> m_s ----
  {
    const int col0 = waveid * 32 + c, col1 = col0 + 16;
    const float g0 = n2g[col0], b0 = n2b[col0];
    const float g1 = n2g[col1], b1 = n2b[col1];
#pragma unroll
    for (int i = 0; i < 4; i++)
#pragma unroll
      for (int r = 0; r < 4; r++) {
        const int n = 16 * i + 4 * quad + r;
        const f32x4 lo = *(const f32x4*)&red_s[n * 16 + 0];
        const f32x4 hi = *(const f32x4*)&red_s[n * 16 + 4];
        const f32x4 qlo = *(const f32x4*)&red_s[n * 16 + 8];
        const f32x4 qhi = *(const f32x4*)&red_s[n * 16 + 12];
        const float s1 = lo[0] + lo[1] + lo[2] + lo[3] + hi[0] + hi[1];
        const float s2 = qlo[0] + qlo[1] + qlo[2] + qlo[3] + qhi[0] + qhi[1];
        const float mu = s1 * (1.f / 192.f);
        const float rinv = rsqrtf(s2 * (1.f / 192.f) - mu * mu + 1e-5f);
        m_s[n * 200 + col0] = (bf16)((hv[i][0][r] - mu) * rinv * g0 + b0);
        m_s[n * 200 + col1] = (bf16)((hv[i][1][r] - mu) * rinv * g1 + b1);
      }
  }
  __syncthreads();   // G: m_s visible

  // ---- ph6: MLP fc1 -> GELU -> fc2 (4 chunks of 192) ----
  f32x4 oacc[4][2];
#pragma unroll
  for (int i = 0; i < 4; i++)
#pragma unroll
    for (int j = 0; j < 2; j++) oacc[i][j] = fzero;

  for (int chunk = 0; chunk < 4; chunk++) {
    f32x4 gacc[4][2];
#pragma unroll
    for (int i = 0; i < 4; i++)
#pragma unroll
      for (int j = 0; j < 2; j++) gacc[i][j] = fzero;
#pragma unroll
    for (int ks = 0; ks < 6; ks++) {
      bf16x8 a[4], w[2];
#pragma unroll
      for (int i = 0; i < 4; i++)
        a[i] = *(const bf16x8*)&m_s[(16 * i + c) * 200 + ks * 32 + quad * 8];
#pragma unroll
      for (int j = 0; j < 2; j++)
        w[j] = *(const bf16x8*)(wfc1 +
            (size_t)(chunk * 192 + waveid * 32 + 16 * j + c) * 192 + ks * 32 + quad * 8);
#pragma unroll
      for (int i = 0; i < 4; i++)
#pragma unroll
        for (int j = 0; j < 2; j++) gacc[i][j] = MFMA16(a[i], w[j], gacc[i][j]);
    }
#pragma unroll
    for (int i = 0; i < 4; i++)
#pragma unroll
      for (int j = 0; j < 2; j++) {
        const int lcol = waveid * 32 + 16 * j + c;
        const float fb = fc1_b[chunk * 192 + lcol];
#pragma unroll
        for (int r = 0; r < 4; r++) {
          float val = gacc[i][j][r] + fb;
          val = 0.5f * val * (1.f + erff(val * 0.70710678118654752f));
          g_s[(16 * i + 4 * quad + r) * 200 + lcol] = (bf16)val;
        }
      }
    __syncthreads();
#pragma unroll
    for (int ks = 0; ks < 6; ks++) {
      bf16x8 a[4], w[2];
#pragma unroll
      for (int i = 0; i < 4; i++)
        a[i] = *(const bf16x8*)&g_s[(16 * i + c) * 200 + ks * 32 + quad * 8];
#pragma unroll
      for (int j = 0; j < 2; j++)
        w[j] = *(const bf16x8*)(wfc2 +
            (size_t)(waveid * 32 + 16 * j + c) * 768 + chunk * 192 + ks * 32 + quad * 8);
#pragma unroll
      for (int i = 0; i < 4; i++)
#pragma unroll
        for (int j = 0; j < 2; j++) oacc[i][j] = MFMA16(a[i], w[j], oacc[i][j]);
    }
    __syncthreads();
  }

  // ---- ph7: epilogue: + fc2_b + h (read back from out), fp32 out ----
#pragma unroll
  for (int i = 0; i < 4; i++)
#pragma unroll
    for (int r = 0; r < 4; r++) {
      const int n = 16 * i + 4 * quad + r;
      const int oh = (wy * 8 + (n >> 3) + 4) & 127;
      const int ow = (wx * 8 + (n & 7) + 4) & 127;
      float* orow = out + (size_t)(bi * 16384 + oh * 128 + ow) * 192;
#pragma unroll
      for (int j = 0; j < 2; j++) {
        const int col = waveid * 32 + 16 * j + c;
        const float h = orow[col];
        orow[col] = oacc[i][j][r] + fc2_b[col] + h;
      }
    }
}

// ---------------- launch ----------------
extern "C" void kernel_launch(void* const* d_in, const int* in_sizes, int n_in,
                              void* d_out, int out_size, void* d_ws, size_t ws_size,
                              hipStream_t stream) {
  const float* x      = (const float*)d_in[0];
  const float* n1g    = (const float*)d_in[1];
  const float* n1b    = (const float*)d_in[2];
  const float* qkv_w  = (const float*)d_in[3];
  const float* qkv_b  = (const float*)d_in[4];
  const float* proj_w = (const float*)d_in[5];
  const float* proj_b = (const float*)d_in[6];
  const float* rpb    = (const float*)d_in[7];
  const float* n2g    = (const float*)d_in[8];
  const float* n2b    = (const float*)d_in[9];
  const float* fc1_w  = (const float*)d_in[10];
  const float* fc1_b  = (const float*)d_in[11];
  const float* fc2_w  = (const float*)d_in[12];
  const float* fc2_b  = (const float*)d_in[13];

  // tiny workspace: 983,040 B total
  char* ws = (char*)d_ws;
  float* biasf = (float*)(ws);                       // 98,304 B
  bf16*  wqkv  = (bf16*)(ws + 98304);                // 221,184 B
  bf16*  wproj = (bf16*)(ws + 98304 + 221184);       // 73,728 B
  bf16*  wfc1  = (bf16*)(ws + 98304 + 221184 + 73728);            // 294,912 B
  bf16*  wfc2  = (bf16*)(ws + 98304 + 221184 + 73728 + 294912);   // 294,912 B

  prep_kernel<<<576, 256, 0, stream>>>(qkv_w, proj_w, fc1_w, fc2_w, rpb,
                                       wqkv, wproj, wfc1, wfc2, biasf);
  swin_block_kernel<<<4096, 384, 0, stream>>>(
      x, n1g, n1b, wqkv, qkv_b, wproj, proj_b, biasf,
      n2g, n2b, wfc1, fc1_b, wfc2, fc2_b, (float*)d_out);
}